// Round 2
// baseline (358.397 us; speedup 1.0000x reference)
//
#include <hip/hip_runtime.h>
#include <math.h>

#define BLOCK 256
#define RB 32            // rows per block -> grid = 512 = 2 blocks/CU
#define BD 64            // K-chunk
#define NE 64            // experts
#define DDIM 2048
#define TOPK 8
#define WP 68            // LDS pitch (dwords) for w rows: 272B, b128 reads conflict-free
#define NCHUNK (DDIM / BD)

typedef float __attribute__((ext_vector_type(4))) f32x4;
// constant-addrspace pointer: forces s_load (SMRD) for wave-uniform x reads
typedef const __attribute__((address_space(4))) f32x4* cf4p;

__global__ __launch_bounds__(BLOCK, 2) void gate_kernel(
    const float* __restrict__ x,      // [NR, D]
    const float* __restrict__ w,      // [E, D]
    const float* __restrict__ bias,   // [E]
    float* __restrict__ out_w,        // [NR, K]
    float* __restrict__ out_i)        // [NR, K] indices as float
{
    __shared__ float ws[2][NE][WP];       // 34.8 KB double-buffered w chunk
    __shared__ float logits[RB][NE + 1];  // 8.3 KB

    const int t    = threadIdx.x;
    const int e    = t & 63;              // lane = expert
    const int rg   = t >> 6;              // wave = row-group
    const int rgu  = __builtin_amdgcn_readfirstlane(rg);
    const int row0 = blockIdx.x * RB;

    float acc[8];
#pragma unroll
    for (int r = 0; r < 8; ++r) acc[r] = 0.f;

    // staging mapping: f4 = t + i*BLOCK; expert row = f4>>4; col = f4&15
    f32x4 stg[4];
#define LOADSTG(c)                                                            \
    {                                                                         \
        const int d0s = (c) * BD;                                             \
        _Pragma("unroll")                                                     \
        for (int i = 0; i < 4; ++i) {                                         \
            int f4 = t + i * BLOCK;                                           \
            int wr = f4 >> 4, wc = f4 & 15;                                   \
            stg[i] = *(const f32x4*)&w[(size_t)wr * DDIM + d0s + wc * 4];     \
        }                                                                     \
    }
#define WRITESTG(buf)                                                         \
    {                                                                         \
        _Pragma("unroll")                                                     \
        for (int i = 0; i < 4; ++i) {                                         \
            int f4 = t + i * BLOCK;                                           \
            int wr = f4 >> 4, wc = f4 & 15;                                   \
            *(f32x4*)&ws[buf][wr][wc * 4] = stg[i];                           \
        }                                                                     \
    }

    LOADSTG(0);
    WRITESTG(0);

    const float* xbase0 = x + (size_t)(row0 + rgu * 8) * DDIM;  // wave-uniform

    int p = 0;
    for (int c = 0; c < NCHUNK; ++c) {
        if (c + 1 < NCHUNK) LOADSTG(c + 1);   // issue next-chunk global loads early
        __syncthreads();                       // ws[p] ready

        // own expert's w chunk: 16 ds_read_b128 -> 64 VGPRs, reused across 8 rows
        f32x4 wv[16];
#pragma unroll
        for (int g = 0; g < 16; ++g)
            wv[g] = *(const f32x4*)&ws[p][e][g * 4];

        if (c + 1 < NCHUNK) WRITESTG(p ^ 1);  // fill other buffer (read of p done above)

        const int d0 = c * BD;
#pragma unroll
        for (int r = 0; r < 8; ++r) {
            // wave-uniform constant-AS pointer -> s_load_dwordx4; x feeds FMA as SGPR
            cf4p xc = (cf4p)(unsigned long long)(xbase0 + (size_t)r * DDIM + d0);
            float a = acc[r];
#pragma unroll
            for (int g = 0; g < 16; ++g) {
                f32x4 xv = xc[g];
                a += wv[g].x * xv.x;
                a += wv[g].y * xv.y;
                a += wv[g].z * xv.z;
                a += wv[g].w * xv.w;
            }
            acc[r] = a;
        }
        p ^= 1;
    }

    // ---- logits to LDS ----
#pragma unroll
    for (int r = 0; r < 8; ++r) logits[rg * 8 + r][e] = acc[r];
    __syncthreads();

    // ---- top-8 per row, wave-parallel, lane = expert ----
    const int lane = e;
    const float bias_l = bias[lane];

    for (int r8 = 0; r8 < 8; ++r8) {
        const int r  = rg * 8 + r8;
        const int gr = row0 + r;
        float raw = logits[r][lane];
        float sig = 1.f / (1.f + expf(-raw));
        float v   = raw + bias_l;

        float wsum = 0.f, myw = 0.f;
        int   myidx = 0;
#pragma unroll
        for (int k = 0; k < TOPK; ++k) {
            float m = v;
#pragma unroll
            for (int off = 32; off; off >>= 1)
                m = fmaxf(m, __shfl_xor(m, off));
            unsigned long long b = __ballot(v == m);
            int idx = (int)__builtin_ctzll(b);          // lowest index wins ties
            float wk = __shfl(sig, idx);
            wsum += wk;                                  // reference summation order
            if (lane == k)  { myw = wk; myidx = idx; }
            if (lane == idx) v = -INFINITY;
        }
        if (lane < TOPK) {
            out_w[(size_t)gr * TOPK + lane] = myw / wsum;
            out_i[(size_t)gr * TOPK + lane] = (float)myidx;
        }
    }
}

extern "C" void kernel_launch(void* const* d_in, const int* in_sizes, int n_in,
                              void* d_out, int out_size, void* d_ws, size_t ws_size,
                              hipStream_t stream) {
    const float* x    = (const float*)d_in[0];
    const float* w    = (const float*)d_in[1];
    const float* bias = (const float*)d_in[2];
    const int NR = in_sizes[0] / DDIM;          // 16384 rows
    float* out   = (float*)d_out;
    float* out_w = out;
    float* out_i = out + (size_t)NR * TOPK;

    dim3 grid(NR / RB), block(BLOCK);
    hipLaunchKernelGGL(gate_kernel, grid, block, 0, stream,
                       x, w, bias, out_w, out_i);
}

// Round 3
// 132.068 us; speedup vs baseline: 2.7137x; 2.7137x over previous
//
#include <hip/hip_runtime.h>
#include <math.h>

#define BLOCK 256
#define RB 16            // rows per block -> grid = 1024
#define BD 128           // K-chunk
#define NE 64
#define DDIM 2048
#define TOPK 8
#define NCHUNK (DDIM / BD)   // 16

typedef float __attribute__((ext_vector_type(4))) f32x4;

__global__ __launch_bounds__(BLOCK, 2) void gate_kernel(
    const float* __restrict__ x,      // [NR, D]
    const float* __restrict__ w,      // [E, D]
    const float* __restrict__ bias,   // [E]
    float* __restrict__ out_w,        // [NR, K]
    float* __restrict__ out_i)        // [NR, K] indices as float
{
    __shared__ float xs[RB * BD];          // 8 KB, linear (global_load_lds dest)
    __shared__ float ws[NE * BD];          // 32 KB, linear
    __shared__ float logits[RB][NE + 1];   // 4.2 KB

    const int t    = threadIdx.x;
    const int lane = t & 63;
    const int wid  = t >> 6;          // 0..3
    const int rw   = wid & 1;         // row half:    rows rw*8 .. rw*8+7
    const int ew   = wid >> 1;        // expert half: experts ew*32 .. +31
    const int kc   = lane & 31;       // K-column group: cols 4kc..4kc+3 of chunk
    const int kh   = lane >> 5;       // sub-half: experts ebase = ew*32 + kh*16
    const int row0 = blockIdx.x * RB;
    const int ebase = ew * 32 + kh * 16;

    float acc[8][16];
#pragma unroll
    for (int r = 0; r < 8; ++r)
#pragma unroll
        for (int j = 0; j < 16; ++j) acc[r][j] = 0.f;

    // chunk staging via global_load_lds (width 16): LDS dest = uniform base + lane*16.
    // x chunk: 8 KB = 8 slices of 1024B; w chunk: 32 KB = 32 slices. Slice s covers
    // linear floats [s*256, s*256+256) of the row-major [rows][BD] chunk image.
#define ISSUE_LOADS(c)                                                         \
    {                                                                          \
        const int d0_ = (c) * BD;                                              \
        _Pragma("unroll")                                                      \
        for (int i = 0; i < 2; ++i) {                                          \
            int s  = wid * 2 + i;                                              \
            int f  = s * 256 + lane * 4;                                       \
            int xr = f >> 7, xc = f & 127;                                     \
            __builtin_amdgcn_global_load_lds(                                  \
                (const __attribute__((address_space(1))) unsigned int*)        \
                    (x + (size_t)(row0 + xr) * DDIM + d0_ + xc),               \
                (__attribute__((address_space(3))) unsigned int*)(xs + s*256), \
                16, 0, 0);                                                     \
        }                                                                      \
        _Pragma("unroll")                                                      \
        for (int i = 0; i < 8; ++i) {                                          \
            int s  = wid * 8 + i;                                              \
            int f  = s * 256 + lane * 4;                                       \
            int wr = f >> 7, wc = f & 127;                                     \
            __builtin_amdgcn_global_load_lds(                                  \
                (const __attribute__((address_space(1))) unsigned int*)        \
                    (w + (size_t)wr * DDIM + d0_ + wc),                        \
                (__attribute__((address_space(3))) unsigned int*)(ws + s*256), \
                16, 0, 0);                                                     \
        }                                                                      \
    }

    ISSUE_LOADS(0);

    for (int c = 0; c < NCHUNK; ++c) {
        __syncthreads();   // barrier drains vmcnt -> chunk c resident in LDS

        // x: 8 full-rate-ish b128 (2-way kh duplication only), reused over 16 experts
        f32x4 xv[8];
#pragma unroll
        for (int r = 0; r < 8; ++r)
            xv[r] = *(const f32x4*)&xs[(rw * 8 + r) * BD + kc * 4];

#pragma unroll
        for (int j = 0; j < 16; ++j) {
            f32x4 wj = *(const f32x4*)&ws[(ebase + j) * BD + kc * 4];
#pragma unroll
            for (int r = 0; r < 8; ++r) {
                acc[r][j] += xv[r].x * wj.x;
                acc[r][j] += xv[r].y * wj.y;
                acc[r][j] += xv[r].z * wj.z;
                acc[r][j] += xv[r].w * wj.w;
            }
        }

        __syncthreads();   // all reads of chunk c complete before overwrite
        if (c + 1 < NCHUNK) ISSUE_LOADS(c + 1);
    }

    // ---- reduce partial sums across the 32 kc-lanes (within each kh half) ----
#pragma unroll
    for (int r = 0; r < 8; ++r) {
#pragma unroll
        for (int j = 0; j < 16; ++j) {
            float v = acc[r][j];
#pragma unroll
            for (int off = 16; off; off >>= 1)
                v += __shfl_xor(v, off);        // xor<=16 stays within 32-lane half
            if (kc == j) logits[rw * 8 + r][ebase + j] = v;
        }
    }
    __syncthreads();

    // ---- top-8 per row, wave-parallel, lane = expert (proven R0 code) ----
    const float bias_l = bias[lane];
    for (int r4 = 0; r4 < 4; ++r4) {
        const int r  = wid * 4 + r4;
        const int gr = row0 + r;
        float raw = logits[r][lane];
        float sig = 1.f / (1.f + expf(-raw));
        float v   = raw + bias_l;

        float wsum = 0.f, myw = 0.f;
        int   myidx = 0;
#pragma unroll
        for (int k = 0; k < TOPK; ++k) {
            float m = v;
#pragma unroll
            for (int off = 32; off; off >>= 1)
                m = fmaxf(m, __shfl_xor(m, off));
            unsigned long long b = __ballot(v == m);
            int idx = (int)__builtin_ctzll(b);          // lowest index wins ties
            float wk = __shfl(sig, idx);
            wsum += wk;                                  // reference summation order
            if (lane == k)  { myw = wk; myidx = idx; }
            if (lane == idx) v = -INFINITY;
        }
        if (lane < TOPK) {
            out_w[(size_t)gr * TOPK + lane] = myw / wsum;
            out_i[(size_t)gr * TOPK + lane] = (float)myidx;
        }
    }
}

extern "C" void kernel_launch(void* const* d_in, const int* in_sizes, int n_in,
                              void* d_out, int out_size, void* d_ws, size_t ws_size,
                              hipStream_t stream) {
    const float* x    = (const float*)d_in[0];
    const float* w    = (const float*)d_in[1];
    const float* bias = (const float*)d_in[2];
    const int NR = in_sizes[0] / DDIM;          // 16384 rows
    float* out   = (float*)d_out;
    float* out_w = out;
    float* out_i = out + (size_t)NR * TOPK;

    dim3 grid(NR / RB), block(BLOCK);
    hipLaunchKernelGGL(gate_kernel, grid, block, 0, stream,
                       x, w, bias, out_w, out_i);
}

// Round 4
// 80.060 us; speedup vs baseline: 4.4766x; 1.6496x over previous
//
#include <hip/hip_runtime.h>
#include <math.h>

#define BLOCK 256
#define RB 32            // rows per block -> grid = 512 = 2 blocks/CU
#define BD 64            // K-chunk
#define NE 64
#define DDIM 2048
#define TOPK 8
#define NCHUNK (DDIM / BD)   // 32

typedef float __attribute__((ext_vector_type(4))) f32x4;

__global__ __launch_bounds__(BLOCK, 2) void gate_kernel(
    const float* __restrict__ x,      // [NR, D]
    const float* __restrict__ w,      // [E, D]
    const float* __restrict__ bias,   // [E]
    float* __restrict__ out_w,        // [NR, K]
    float* __restrict__ out_i)        // [NR, K] indices as float
{
    __shared__ float xs[2][RB * BD];   // 2 x 8 KB, linear (global_load_lds dest)
    __shared__ float ws[2][NE * BD];   // 2 x 16 KB, linear

    const int t    = threadIdx.x;
    const int lane = t & 63;
    const int wid  = t >> 6;          // wave id: owns rows wid*8 .. wid*8+7
    const int kc   = lane & 15;       // col group: cols 4kc..4kc+3 of chunk
    const int kh   = lane >> 4;       // expert group: experts kh*16 .. +15
    const int row0 = blockIdx.x * RB;

    float acc[8][16];
#pragma unroll
    for (int r = 0; r < 8; ++r)
#pragma unroll
        for (int j = 0; j < 16; ++j) acc[r][j] = 0.f;

    // Staging: chunk images row-major [rows][BD]. 1KB slices; lane writes
    // uniform-base + lane*16 (global_load_lds constraint). x: 8 slices, w: 16.
#define ISSUE(c_, xb_, wb_)                                                    \
    {                                                                          \
        const int d0_ = (c_) * BD;                                             \
        _Pragma("unroll")                                                      \
        for (int i = 0; i < 2; ++i) {                                          \
            int s  = wid * 2 + i;                                              \
            int f  = s * 256 + lane * 4;                                       \
            int xr = f >> 6, xc = f & 63;                                      \
            __builtin_amdgcn_global_load_lds(                                  \
                (const __attribute__((address_space(1))) unsigned int*)        \
                    (x + (size_t)(row0 + xr) * DDIM + d0_ + xc),               \
                (__attribute__((address_space(3))) unsigned int*)((xb_) + s * 256), \
                16, 0, 0);                                                     \
        }                                                                      \
        _Pragma("unroll")                                                      \
        for (int i = 0; i < 4; ++i) {                                          \
            int s  = wid * 4 + i;                                              \
            int f  = s * 256 + lane * 4;                                       \
            int wr = f >> 6, wc = f & 63;                                      \
            __builtin_amdgcn_global_load_lds(                                  \
                (const __attribute__((address_space(1))) unsigned int*)        \
                    (w + (size_t)wr * DDIM + d0_ + wc),                        \
                (__attribute__((address_space(3))) unsigned int*)((wb_) + s * 256), \
                16, 0, 0);                                                     \
        }                                                                      \
    }

    ISSUE(0, xs[0], ws[0]);

    for (int c = 0; c < NCHUNK; ++c) {
        __syncthreads();   // implicit vmcnt(0): chunk c resident; prior buffer reads done

        const float* xsb = xs[c & 1];
        const float* wsb = ws[c & 1];
        // issue next chunk into the other buffer; drains at NEXT barrier,
        // one full compute phase away -> latency hidden
        if (c + 1 < NCHUNK) ISSUE(c + 1, xs[(c + 1) & 1], ws[(c + 1) & 1]);

        f32x4 xv[8];
#pragma unroll
        for (int r = 0; r < 8; ++r)
            xv[r] = *(const f32x4*)&xsb[(wid * 8 + r) * BD + kc * 4];

#pragma unroll
        for (int j = 0; j < 16; ++j) {
            f32x4 wj = *(const f32x4*)&wsb[(kh * 16 + j) * BD + kc * 4];
#pragma unroll
            for (int r = 0; r < 8; ++r) {
                acc[r][j] += xv[r].x * wj.x;
                acc[r][j] += xv[r].y * wj.y;
                acc[r][j] += xv[r].z * wj.z;
                acc[r][j] += xv[r].w * wj.w;
            }
        }
    }

    // ---- epilogue: per row, fold-transpose 16 partials over the 16 kc-lanes
    // so that lane l ends holding the full logit of expert l; then top-8.
    const float bias_l = bias[lane];

#pragma unroll
    for (int r = 0; r < 8; ++r) {
        const int gr = row0 + wid * 8 + r;

        float v[16];
#pragma unroll
        for (int j = 0; j < 16; ++j) v[j] = acc[r][j];
#pragma unroll
        for (int o = 8; o; o >>= 1) {       // fold 2o elems -> o, exchanging halves
            bool hi = (kc & o) != 0;
#pragma unroll
            for (int j = 0; j < o; ++j) {
                float send = hi ? v[j] : v[j + o];
                float keep = hi ? v[j + o] : v[j];
                v[j] = keep + __shfl_xor(send, o);
            }
        }
        float raw = v[0];                   // logit[row][expert=lane]
        float sig = 1.f / (1.f + expf(-raw));
        float vv  = raw + bias_l;

        float wsum = 0.f, myw = 0.f;
        int   myidx = 0;
#pragma unroll
        for (int k = 0; k < TOPK; ++k) {
            float m = vv;
#pragma unroll
            for (int off = 32; off; off >>= 1)
                m = fmaxf(m, __shfl_xor(m, off));
            unsigned long long b = __ballot(vv == m);
            int idx = (int)__builtin_ctzll(b);          // lowest index wins ties
            float wk = __shfl(sig, idx);
            wsum += wk;                                  // reference summation order
            if (lane == k)  { myw = wk; myidx = idx; }
            if (lane == idx) vv = -INFINITY;
        }
        if (lane < TOPK) {
            out_w[(size_t)gr * TOPK + lane] = myw / wsum;
            out_i[(size_t)gr * TOPK + lane] = (float)myidx;
        }
    }
}

extern "C" void kernel_launch(void* const* d_in, const int* in_sizes, int n_in,
                              void* d_out, int out_size, void* d_ws, size_t ws_size,
                              hipStream_t stream) {
    const float* x    = (const float*)d_in[0];
    const float* w    = (const float*)d_in[1];
    const float* bias = (const float*)d_in[2];
    const int NR = in_sizes[0] / DDIM;          // 16384 rows
    float* out   = (float*)d_out;
    float* out_w = out;
    float* out_i = out + (size_t)NR * TOPK;

    dim3 grid(NR / RB), block(BLOCK);
    hipLaunchKernelGGL(gate_kernel, grid, block, 0, stream,
                       x, w, bias, out_w, out_i);
}